// Round 13
// baseline (11737.457 us; speedup 1.0000x reference)
//
#include <hip/hip_runtime.h>
#include <hip/hip_bf16.h>
#include <cstdint>

// ChromaticResonance R13: free AGPRs to buy B-prefetch depth.
// R12 was latency-stalled: 124 arch + 128 AGPR = 252/256, no room to keep
// >1 ks of B loads in flight; 2 waves/SIMD can't hide L2 latency -> >80%
// idle. Split c into two halves (2 chunks each): acc 128->64 AGPR, ~60
// spare regs -> scheduler hoists B loads >=2 ks ahead. ks fully unrolled
// (static indexing). A-LDS traffic x2 (overlapped). Math/order identical
// to R12 -> absmax bitwise 0.01757812.
// packed B: [t:32][ks:16][f:6][512] u16, f = {o0h, o0l, o1h, o2h, o3h, o3l}.

typedef __bf16 bf16_t;
typedef bf16_t bf16x8 __attribute__((ext_vector_type(8)));
typedef float f32x4 __attribute__((ext_vector_type(4)));
typedef _Float16 h2_t __attribute__((ext_vector_type(2)));

#define B_ROWS 32768
#define D_DIM 512
#define N_DEPTH 7
#define BD ((size_t)B_ROWS * D_DIM)

__device__ __forceinline__ unsigned short f2b(float f) {
  bf16_t h = (bf16_t)f;
  return __builtin_bit_cast(unsigned short, h);
}
__device__ __forceinline__ float b2f(unsigned short u) {
  bf16_t h = __builtin_bit_cast(bf16_t, u);
  return (float)h;
}
__device__ __forceinline__ float fast_tanh(float x) {
  float ax = fabsf(x);
  float e = __expf(2.0f * ax);
  float t = 1.0f - 2.0f / (e + 1.0f);
  return copysignf(t, x);
}
// LDS plane: [32 rows][512 bf16], 1KB/row, XOR swizzle on bits 4-6.
__device__ __forceinline__ int lds_addr(int row, int byte_in_row) {
  return row * 1024 + (byte_in_row ^ ((row & 7) << 4));
}

// B-fragment map (mfma_f32_16x16x32_bf16): col = lane&15, k = (lane>>4)*8+i.
__global__ __launch_bounds__(256) void prepack_v2(
    const float* __restrict__ cm, const float* __restrict__ h1,
    const float* __restrict__ h2, const float* __restrict__ h3,
    const float* __restrict__ h5, unsigned short* __restrict__ dst) {
  int gid = blockIdx.x * 256 + threadIdx.x;  // 0..32767
  if (gid >= 32 * 16 * 64) return;
  int l  = gid & 63;
  int ks = (gid >> 6) & 15;
  int t  = gid >> 10;
  int n  = t * 16 + (l & 15);
  int k0 = ks * 32 + (l >> 4) * 8;
  unsigned short* base = dst + ((size_t)(t * 16 + ks) * 6) * 512 + l * 8;
  bf16x8 f0, f1, f2, f3, f4, f5;
#pragma unroll
  for (int i = 0; i < 8; ++i) {
    size_t idx = (size_t)(k0 + i) * D_DIM + n;
    float v0 = cm[idx] + h1[idx];
    unsigned short h0 = f2b(v0);
    f0[i] = __builtin_bit_cast(bf16_t, h0);
    f1[i] = (bf16_t)(v0 - b2f(h0));
    f2[i] = (bf16_t)h2[idx];
    f3[i] = (bf16_t)h3[idx];
    float v5 = h5[idx];
    unsigned short h5v = f2b(v5);
    f4[i] = __builtin_bit_cast(bf16_t, h5v);
    f5[i] = (bf16_t)(v5 - b2f(h5v));
  }
  *(bf16x8*)(base + 0 * 512) = f0;
  *(bf16x8*)(base + 1 * 512) = f1;
  *(bf16x8*)(base + 2 * 512) = f2;
  *(bf16x8*)(base + 3 * 512) = f3;
  *(bf16x8*)(base + 4 * 512) = f4;
  *(bf16x8*)(base + 5 * 512) = f5;
}

__global__ __launch_bounds__(512) void resonance_kernel(
    const float* __restrict__ wr, const float* __restrict__ wi,
    const float* __restrict__ scale, const float* __restrict__ bias,
    const unsigned short* __restrict__ pre, float* __restrict__ out) {
  __shared__ unsigned short lds_hi[2][32 * 512];  // 2 x 32KB
  __shared__ unsigned short lds_lo[2][32 * 512];  // 2 x 32KB

  const int tid  = threadIdx.x;
  const int lane = tid & 63;
  const int wave = tid >> 6;   // 0..7
  const int ln15 = lane & 15;
  const int lg   = lane >> 4;  // 0..3
  const int r0   = blockIdx.x * 16;  // 16 complex rows per block

  // ---- stage initial wave into buffer 0 (GEMM rows: 0-15 re, 16-31 im) ----
#pragma unroll
  for (int it = 0; it < 4; ++it) {
    int idx = it * 512 + tid;  // 0..2047, 8 elems each
    int row = idx >> 6;        // 0..31
    int k0  = (idx & 63) * 8;
    const float* src = (row < 16)
        ? (wr + (size_t)(r0 + row) * D_DIM + k0)
        : (wi + (size_t)(r0 + row - 16) * D_DIM + k0);
    float4 v0 = *(const float4*)(src);
    float4 v1 = *(const float4*)(src + 4);
    float v[8] = {v0.x, v0.y, v0.z, v0.w, v1.x, v1.y, v1.z, v1.w};
    bf16x8 ph, pl;
#pragma unroll
    for (int j = 0; j < 8; ++j) {
      unsigned short h = f2b(v[j]);
      ph[j] = __builtin_bit_cast(bf16_t, h);
      pl[j] = (bf16_t)(v[j] - b2f(h));
    }
    int ad = lds_addr(row, k0 * 2);
    *(bf16x8*)((char*)lds_hi[0] + ad) = ph;
    *(bf16x8*)((char*)lds_lo[0] + ad) = pl;
  }
  __syncthreads();

  float Wsum = 0.0f;
#pragma unroll
  for (int d = 0; d < N_DEPTH; ++d) Wsum += __expf(-(float)d * (1.0f / 3.0f));
  const float invW = 1.0f / Wsum;

  h2_t oacc[4][4];  // [chunk][r] packed fp16 (re, im) output accumulator
#pragma unroll
  for (int c = 0; c < 4; ++c)
#pragma unroll
    for (int r = 0; r < 4; ++r) oacc[c][r] = (h2_t){(_Float16)0.f, (_Float16)0.f};

  int cur = 0;
  for (int depth = 0; depth < N_DEPTH; ++depth) {
    const float wd = __expf(-(float)depth * (1.0f / 3.0f)) * invW;
    const char* Ahi = (const char*)lds_hi[cur];
    const char* Alo = (const char*)lds_lo[cur];
    char* Nhi = (char*)lds_hi[cur ^ 1];
    char* Nlo = (char*)lds_lo[cur ^ 1];

#pragma unroll
    for (int half = 0; half < 2; ++half) {
      f32x4 acc0[2][2], acc1[2][2], acc2[2][2], acc3[2][2];  // [ci][mt] 64 AGPR
#pragma unroll
      for (int ci = 0; ci < 2; ++ci)
#pragma unroll
        for (int mt = 0; mt < 2; ++mt) {
          acc0[ci][mt] = (f32x4){0.f, 0.f, 0.f, 0.f};
          acc1[ci][mt] = (f32x4){0.f, 0.f, 0.f, 0.f};
          acc2[ci][mt] = (f32x4){0.f, 0.f, 0.f, 0.f};
          acc3[ci][mt] = (f32x4){0.f, 0.f, 0.f, 0.f};
        }

      const unsigned short* bp[2];
#pragma unroll
      for (int ci = 0; ci < 2; ++ci)
        bp[ci] = pre +
            ((size_t)(((half * 2 + ci) * 8 + wave) * 16) * 6 + 3) * 512 + lane * 8;

#pragma unroll
      for (int ks = 0; ks < 16; ++ks) {
        bf16x8 ah[2], al[2];  // one A-load pair feeds both chunks
#pragma unroll
        for (int mt = 0; mt < 2; ++mt) {
          int ad = lds_addr(mt * 16 + ln15, ks * 64 + lg * 16);
          ah[mt] = *(const bf16x8*)(Ahi + ad);
          al[mt] = *(const bf16x8*)(Alo + ad);
        }
#pragma unroll
        for (int ci = 0; ci < 2; ++ci) {
          const unsigned short* bb = bp[ci] + ks * 3072;
          bf16x8 b0h = *(const bf16x8*)(bb - 1536);
          bf16x8 b0l = *(const bf16x8*)(bb - 1024);
          bf16x8 b1h = *(const bf16x8*)(bb - 512);
          bf16x8 b2h = *(const bf16x8*)(bb);
          bf16x8 b3h = *(const bf16x8*)(bb + 512);
          bf16x8 b3l = *(const bf16x8*)(bb + 1024);
#pragma unroll
          for (int mt = 0; mt < 2; ++mt) {
            acc0[ci][mt] = __builtin_amdgcn_mfma_f32_16x16x32_bf16(ah[mt], b0h, acc0[ci][mt], 0, 0, 0);
            acc0[ci][mt] = __builtin_amdgcn_mfma_f32_16x16x32_bf16(al[mt], b0h, acc0[ci][mt], 0, 0, 0);
            acc0[ci][mt] = __builtin_amdgcn_mfma_f32_16x16x32_bf16(ah[mt], b0l, acc0[ci][mt], 0, 0, 0);
            acc1[ci][mt] = __builtin_amdgcn_mfma_f32_16x16x32_bf16(ah[mt], b1h, acc1[ci][mt], 0, 0, 0);
            acc2[ci][mt] = __builtin_amdgcn_mfma_f32_16x16x32_bf16(ah[mt], b2h, acc2[ci][mt], 0, 0, 0);
            acc3[ci][mt] = __builtin_amdgcn_mfma_f32_16x16x32_bf16(ah[mt], b3h, acc3[ci][mt], 0, 0, 0);
            acc3[ci][mt] = __builtin_amdgcn_mfma_f32_16x16x32_bf16(al[mt], b3h, acc3[ci][mt], 0, 0, 0);
            acc3[ci][mt] = __builtin_amdgcn_mfma_f32_16x16x32_bf16(ah[mt], b3l, acc3[ci][mt], 0, 0, 0);
          }
        }
      }

      // ---- elementwise for this half's 2 chunks ----
#pragma unroll
      for (int ci = 0; ci < 2; ++ci) {
        const int c = half * 2 + ci;
        const int t = c * 8 + wave;
        const int col = t * 16 + ln15;
        const float sclv = scale[col];
        const float biav = bias[col];
        const float damp = 0.1f / (1.0f + __expf(3.0f * (float)col * (1.0f / 511.0f)));
        const float fac  = __expf(-damp * (float)depth);
#pragma unroll
        for (int r = 0; r < 4; ++r) {
          const int brow = lg * 4 + r;  // complex row 0..15
          float lr = acc0[ci][0][r],  li = acc0[ci][1][r];   // coupling + h1
          float re2 = acc1[ci][0][r], im2 = acc1[ci][1][r];
          float ar = 0.25f * (re2 * re2 + im2 * im2);        // h2 real
          float re3 = acc2[ci][0][r], im3 = acc2[ci][1][r];
          float m3 = re3 * re3 + im3 * im3;
          ar += 0.111111111f * m3 * re3;                     // h3
          float ai = 0.111111111f * m3 * im3;
          float re5 = acc3[ci][0][r], im5 = acc3[ci][1][r];
          float m5 = re5 * re5 + im5 * im5;
          {
            // h5 = |hw|^(1/5) exp(i 5 ang) / 25
            float m5c = fmaxf(m5, 1e-36f);
            float inv = rsqrtf(m5c);
            float ur = re5 * inv, ui = im5 * inv;
            float u2r = ur * ur - ui * ui,     u2i = 2.0f * ur * ui;
            float u4r = u2r * u2r - u2i * u2i, u4i = 2.0f * u2r * u2i;
            float u5r = u4r * ur - u4i * ui,   u5i = u4r * ui + u4i * ur;
            float mag = __expf(0.1f * __logf(m5c));
            float msk = (m5 > 1e-36f) ? 0.04f : 0.0f;
            ar += msk * mag * u5r;
            ai += msk * mag * u5i;
          }
          float ir = lr + ar, ii = li + ai;
          const int colb = col * 2;
          const int ar_ = lds_addr(brow, colb);
          const int ai_ = lds_addr(brow + 16, colb);
          if (depth > 0) {  // interference: old chamber = cur buffer (hi+lo)
            ir += b2f(*(const unsigned short*)(Ahi + ar_))
                + b2f(*(const unsigned short*)(Alo + ar_));
            ii += b2f(*(const unsigned short*)(Ahi + ai_))
                + b2f(*(const unsigned short*)(Alo + ai_));
          }
          float cre = fast_tanh(ir * sclv + biav) * fac;
          float cim = fast_tanh(ii * sclv + biav) * fac;
          oacc[c][r] += (h2_t){(_Float16)(wd * cre), (_Float16)(wd * cim)};
          if (depth < N_DEPTH - 1) {  // state into next buffer
            unsigned short hr = f2b(cre);
            unsigned short hi = f2b(cim);
            *(unsigned short*)(Nhi + ar_) = hr;
            *(unsigned short*)(Nlo + ar_) = f2b(cre - b2f(hr));
            *(unsigned short*)(Nhi + ai_) = hi;
            *(unsigned short*)(Nlo + ai_) = f2b(cim - b2f(hi));
          }
        }
      }
    }
    __syncthreads();  // next buffer fully written before next depth reads it
    cur ^= 1;
  }

  // ---- write weighted sum ----
#pragma unroll
  for (int c = 0; c < 4; ++c) {
    const int col = (c * 8 + wave) * 16 + ln15;
#pragma unroll
    for (int r = 0; r < 4; ++r) {
      int brow = lg * 4 + r;
      size_t base = (size_t)(r0 + brow) * D_DIM + col;
      out[base] = (float)oacc[c][r][0];
      out[BD + base] = (float)oacc[c][r][1];
    }
  }
}

extern "C" void kernel_launch(void* const* d_in, const int* in_sizes, int n_in,
                              void* d_out, int out_size, void* d_ws, size_t ws_size,
                              hipStream_t stream) {
  const float* wr = (const float*)d_in[0];
  const float* wi = (const float*)d_in[1];
  const float* cm = (const float*)d_in[2];
  const float* h1 = (const float*)d_in[3];
  const float* h2 = (const float*)d_in[4];
  const float* h3 = (const float*)d_in[5];
  const float* h5 = (const float*)d_in[6];
  const float* sc = (const float*)d_in[7];
  const float* bi = (const float*)d_in[8];
  unsigned short* pre = (unsigned short*)d_ws;  // 3MB packed B
  float* out = (float*)d_out;

  hipLaunchKernelGGL(prepack_v2, dim3(128), dim3(256), 0, stream,
                     cm, h1, h2, h3, h5, pre);
  hipLaunchKernelGGL(resonance_kernel, dim3(B_ROWS / 16), dim3(512), 0, stream,
                     wr, wi, sc, bi, pre, out);
}

// Round 14
// 2906.177 us; speedup vs baseline: 4.0388x; 4.0388x over previous
//
#include <hip/hip_runtime.h>
#include <hip/hip_bf16.h>
#include <cstdint>

// ChromaticResonance R14: halve the B/L2 wall via 32-row blocks.
// R12 floor analysis: B-stream 43GB L2 (~1.25ms) dominates. 32 complex
// rows/block -> 1024 blocks -> 21.5GB (~0.63ms floor); each B frag feeds
// 4 MFMAs (2x arithmetic intensity). Fits registers via: c-outer (64 AGPR),
// single-buffer 128KB LDS state + R6 two-barrier scheme, interference from
// LDS hi+lo, oacc deleted (fp32 RMW into d_out, depth0 stores), news kept
// (32 regs), ks rolled. Arch ~118 <= 128, total ~182 <= 256 @ 2 waves/SIMD.
// R13 lesson applied: NO full unroll.
// packed B: [t:32][ks:16][f:6][512] u16, f = {o0h, o0l, o1h, o2h, o3h, o3l}.

typedef __bf16 bf16_t;
typedef bf16_t bf16x8 __attribute__((ext_vector_type(8)));
typedef float f32x4 __attribute__((ext_vector_type(4)));
typedef _Float16 h2_t __attribute__((ext_vector_type(2)));

#define B_ROWS 32768
#define D_DIM 512
#define N_DEPTH 7
#define BD ((size_t)B_ROWS * D_DIM)

__device__ __forceinline__ unsigned short f2b(float f) {
  bf16_t h = (bf16_t)f;
  return __builtin_bit_cast(unsigned short, h);
}
__device__ __forceinline__ float b2f(unsigned short u) {
  bf16_t h = __builtin_bit_cast(bf16_t, u);
  return (float)h;
}
__device__ __forceinline__ float fast_tanh(float x) {
  float ax = fabsf(x);
  float e = __expf(2.0f * ax);
  float t = 1.0f - 2.0f / (e + 1.0f);
  return copysignf(t, x);
}
// LDS plane: [64 rows][512 bf16], 1KB/row, XOR swizzle on bits 4-6.
__device__ __forceinline__ int lds_addr(int row, int byte_in_row) {
  return row * 1024 + (byte_in_row ^ ((row & 7) << 4));
}

// B-fragment map (mfma_f32_16x16x32_bf16): col = lane&15, k = (lane>>4)*8+i.
__global__ __launch_bounds__(256) void prepack_v2(
    const float* __restrict__ cm, const float* __restrict__ h1,
    const float* __restrict__ h2, const float* __restrict__ h3,
    const float* __restrict__ h5, unsigned short* __restrict__ dst) {
  int gid = blockIdx.x * 256 + threadIdx.x;  // 0..32767
  if (gid >= 32 * 16 * 64) return;
  int l  = gid & 63;
  int ks = (gid >> 6) & 15;
  int t  = gid >> 10;
  int n  = t * 16 + (l & 15);
  int k0 = ks * 32 + (l >> 4) * 8;
  unsigned short* base = dst + ((size_t)(t * 16 + ks) * 6) * 512 + l * 8;
  bf16x8 f0, f1, f2, f3, f4, f5;
#pragma unroll
  for (int i = 0; i < 8; ++i) {
    size_t idx = (size_t)(k0 + i) * D_DIM + n;
    float v0 = cm[idx] + h1[idx];
    unsigned short h0 = f2b(v0);
    f0[i] = __builtin_bit_cast(bf16_t, h0);
    f1[i] = (bf16_t)(v0 - b2f(h0));
    f2[i] = (bf16_t)h2[idx];
    f3[i] = (bf16_t)h3[idx];
    float v5 = h5[idx];
    unsigned short h5v = f2b(v5);
    f4[i] = __builtin_bit_cast(bf16_t, h5v);
    f5[i] = (bf16_t)(v5 - b2f(h5v));
  }
  *(bf16x8*)(base + 0 * 512) = f0;
  *(bf16x8*)(base + 1 * 512) = f1;
  *(bf16x8*)(base + 2 * 512) = f2;
  *(bf16x8*)(base + 3 * 512) = f3;
  *(bf16x8*)(base + 4 * 512) = f4;
  *(bf16x8*)(base + 5 * 512) = f5;
}

__global__ __launch_bounds__(512) void resonance_kernel(
    const float* __restrict__ wr, const float* __restrict__ wi,
    const float* __restrict__ scale, const float* __restrict__ bias,
    const unsigned short* __restrict__ pre, float* __restrict__ out) {
  __shared__ unsigned short lds_hi[64 * 512];  // 64KB
  __shared__ unsigned short lds_lo[64 * 512];  // 64KB

  const int tid  = threadIdx.x;
  const int lane = tid & 63;
  const int wave = tid >> 6;   // 0..7
  const int ln15 = lane & 15;
  const int lg   = lane >> 4;  // 0..3
  const int r0   = blockIdx.x * 32;  // 32 complex rows per block

  // ---- stage initial wave (GEMM rows: 0-31 re, 32-63 im) ----
#pragma unroll
  for (int it = 0; it < 8; ++it) {
    int idx = it * 512 + tid;  // 0..4095, 8 elems each
    int row = idx >> 6;        // 0..63
    int k0  = (idx & 63) * 8;
    const float* src = (row < 32)
        ? (wr + (size_t)(r0 + row) * D_DIM + k0)
        : (wi + (size_t)(r0 + row - 32) * D_DIM + k0);
    float4 v0 = *(const float4*)(src);
    float4 v1 = *(const float4*)(src + 4);
    float v[8] = {v0.x, v0.y, v0.z, v0.w, v1.x, v1.y, v1.z, v1.w};
    bf16x8 ph, pl;
#pragma unroll
    for (int j = 0; j < 8; ++j) {
      unsigned short h = f2b(v[j]);
      ph[j] = __builtin_bit_cast(bf16_t, h);
      pl[j] = (bf16_t)(v[j] - b2f(h));
    }
    int ad = lds_addr(row, k0 * 2);
    *(bf16x8*)((char*)lds_hi + ad) = ph;
    *(bf16x8*)((char*)lds_lo + ad) = pl;
  }
  __syncthreads();

  float Wsum = 0.0f;
#pragma unroll
  for (int d = 0; d < N_DEPTH; ++d) Wsum += __expf(-(float)d * (1.0f / 3.0f));
  const float invW = 1.0f / Wsum;

  h2_t news[4][8];  // [chunk][mtp*4+r] packed fp16 new chamber state

  for (int depth = 0; depth < N_DEPTH; ++depth) {
    const float wd = __expf(-(float)depth * (1.0f / 3.0f)) * invW;

#pragma unroll
    for (int c = 0; c < 4; ++c) {
      const int t = c * 8 + wave;
      f32x4 acc0[4], acc1[4], acc2[4], acc3[4];  // [mt] 64 AGPR
#pragma unroll
      for (int mt = 0; mt < 4; ++mt) {
        acc0[mt] = (f32x4){0.f, 0.f, 0.f, 0.f};
        acc1[mt] = (f32x4){0.f, 0.f, 0.f, 0.f};
        acc2[mt] = (f32x4){0.f, 0.f, 0.f, 0.f};
        acc3[mt] = (f32x4){0.f, 0.f, 0.f, 0.f};
      }

      const unsigned short* bb = pre + ((size_t)(t * 16) * 6 + 3) * 512 + lane * 8;
#pragma unroll 1
      for (int ks = 0; ks < 16; ++ks) {
        bf16x8 ah[4], al[4];
#pragma unroll
        for (int mt = 0; mt < 4; ++mt) {
          int ad = lds_addr(mt * 16 + ln15, ks * 64 + lg * 16);
          ah[mt] = *(const bf16x8*)((const char*)lds_hi + ad);
          al[mt] = *(const bf16x8*)((const char*)lds_lo + ad);
        }
        bf16x8 b0h = *(const bf16x8*)(bb - 1536);
        bf16x8 b0l = *(const bf16x8*)(bb - 1024);
        bf16x8 b1h = *(const bf16x8*)(bb - 512);
        bf16x8 b2h = *(const bf16x8*)(bb);
        bf16x8 b3h = *(const bf16x8*)(bb + 512);
        bf16x8 b3l = *(const bf16x8*)(bb + 1024);
        bb += 3072;
#pragma unroll
        for (int mt = 0; mt < 4; ++mt) {
          acc0[mt] = __builtin_amdgcn_mfma_f32_16x16x32_bf16(ah[mt], b0h, acc0[mt], 0, 0, 0);
          acc0[mt] = __builtin_amdgcn_mfma_f32_16x16x32_bf16(al[mt], b0h, acc0[mt], 0, 0, 0);
          acc0[mt] = __builtin_amdgcn_mfma_f32_16x16x32_bf16(ah[mt], b0l, acc0[mt], 0, 0, 0);
          acc1[mt] = __builtin_amdgcn_mfma_f32_16x16x32_bf16(ah[mt], b1h, acc1[mt], 0, 0, 0);
          acc2[mt] = __builtin_amdgcn_mfma_f32_16x16x32_bf16(ah[mt], b2h, acc2[mt], 0, 0, 0);
          acc3[mt] = __builtin_amdgcn_mfma_f32_16x16x32_bf16(ah[mt], b3h, acc3[mt], 0, 0, 0);
          acc3[mt] = __builtin_amdgcn_mfma_f32_16x16x32_bf16(al[mt], b3h, acc3[mt], 0, 0, 0);
          acc3[mt] = __builtin_amdgcn_mfma_f32_16x16x32_bf16(ah[mt], b3l, acc3[mt], 0, 0, 0);
        }
      }

      // ---- elementwise: complex rows mtp*16+lg*4+r, col t*16+ln15 ----
      const int col = t * 16 + ln15;
      const float sclv = scale[col];
      const float biav = bias[col];
      const float damp = 0.1f / (1.0f + __expf(3.0f * (float)col * (1.0f / 511.0f)));
      const float fac  = __expf(-damp * (float)depth);
#pragma unroll
      for (int mtp = 0; mtp < 2; ++mtp) {
#pragma unroll
        for (int r = 0; r < 4; ++r) {
          const int brow = mtp * 16 + lg * 4 + r;  // complex row 0..31
          float lr = acc0[mtp][r],  li = acc0[mtp + 2][r];   // coupling + h1
          float re2 = acc1[mtp][r], im2 = acc1[mtp + 2][r];
          float ar = 0.25f * (re2 * re2 + im2 * im2);        // h2 real
          float re3 = acc2[mtp][r], im3 = acc2[mtp + 2][r];
          float m3 = re3 * re3 + im3 * im3;
          ar += 0.111111111f * m3 * re3;                     // h3
          float ai = 0.111111111f * m3 * im3;
          float re5 = acc3[mtp][r], im5 = acc3[mtp + 2][r];
          float m5 = re5 * re5 + im5 * im5;
          {
            // h5 = |hw|^(1/5) exp(i 5 ang) / 25
            float m5c = fmaxf(m5, 1e-36f);
            float inv = rsqrtf(m5c);
            float ur = re5 * inv, ui = im5 * inv;
            float u2r = ur * ur - ui * ui,     u2i = 2.0f * ur * ui;
            float u4r = u2r * u2r - u2i * u2i, u4i = 2.0f * u2r * u2i;
            float u5r = u4r * ur - u4i * ui,   u5i = u4r * ui + u4i * ur;
            float mag = __expf(0.1f * __logf(m5c));
            float msk = (m5 > 1e-36f) ? 0.04f : 0.0f;
            ar += msk * mag * u5r;
            ai += msk * mag * u5i;
          }
          float ir = lr + ar, ii = li + ai;
          const int colb = col * 2;
          const int ar_ = lds_addr(brow, colb);
          const int ai_ = lds_addr(brow + 32, colb);
          if (depth > 0) {  // interference: old chamber from LDS (hi+lo)
            ir += b2f(*(const unsigned short*)((const char*)lds_hi + ar_))
                + b2f(*(const unsigned short*)((const char*)lds_lo + ar_));
            ii += b2f(*(const unsigned short*)((const char*)lds_hi + ai_))
                + b2f(*(const unsigned short*)((const char*)lds_lo + ai_));
          }
          float cre = fast_tanh(ir * sclv + biav) * fac;
          float cim = fast_tanh(ii * sclv + biav) * fac;
          news[c][mtp * 4 + r] = (h2_t){(_Float16)cre, (_Float16)cim};
          // out: fp32 accumulate in-place (depth 0 initializes)
          size_t base = (size_t)(r0 + brow) * D_DIM + col;
          float ore = wd * cre, oim = wd * cim;
          if (depth > 0) { ore += out[base]; oim += out[BD + base]; }
          out[base] = ore;
          out[BD + base] = oim;
        }
      }
    }

    if (depth < N_DEPTH - 1) {
      __syncthreads();  // all GEMM A-reads + interference reads done
#pragma unroll
      for (int c = 0; c < 4; ++c) {
        const int colb = ((c * 8 + wave) * 16 + ln15) * 2;
#pragma unroll
        for (int mtp = 0; mtp < 2; ++mtp) {
#pragma unroll
          for (int r = 0; r < 4; ++r) {
            const int brow = mtp * 16 + lg * 4 + r;
            float cre = (float)news[c][mtp * 4 + r][0];
            float cim = (float)news[c][mtp * 4 + r][1];
            unsigned short hr = f2b(cre);
            unsigned short hi = f2b(cim);
            int ar_ = lds_addr(brow, colb);
            int ai_ = lds_addr(brow + 32, colb);
            *(unsigned short*)((char*)lds_hi + ar_) = hr;
            *(unsigned short*)((char*)lds_lo + ar_) = f2b(cre - b2f(hr));
            *(unsigned short*)((char*)lds_hi + ai_) = hi;
            *(unsigned short*)((char*)lds_lo + ai_) = f2b(cim - b2f(hi));
          }
        }
      }
      __syncthreads();  // new state visible before next depth's GEMM
    }
  }
}

extern "C" void kernel_launch(void* const* d_in, const int* in_sizes, int n_in,
                              void* d_out, int out_size, void* d_ws, size_t ws_size,
                              hipStream_t stream) {
  const float* wr = (const float*)d_in[0];
  const float* wi = (const float*)d_in[1];
  const float* cm = (const float*)d_in[2];
  const float* h1 = (const float*)d_in[3];
  const float* h2 = (const float*)d_in[4];
  const float* h3 = (const float*)d_in[5];
  const float* h5 = (const float*)d_in[6];
  const float* sc = (const float*)d_in[7];
  const float* bi = (const float*)d_in[8];
  unsigned short* pre = (unsigned short*)d_ws;  // 3MB packed B
  float* out = (float*)d_out;

  hipLaunchKernelGGL(prepack_v2, dim3(128), dim3(256), 0, stream,
                     cm, h1, h2, h3, h5, pre);
  hipLaunchKernelGGL(resonance_kernel, dim3(B_ROWS / 32), dim3(512), 0, stream,
                     wr, wi, sc, bi, pre, out);
}

// Round 15
// 2006.374 us; speedup vs baseline: 5.8501x; 1.4485x over previous
//
#include <hip/hip_runtime.h>
#include <hip/hip_bf16.h>
#include <cstdint>

// ChromaticResonance R15: R13's AGPR-freeing + R12's rolled-loop discipline.
// R12 is latency-stalled: 124 arch + 128 AGPR = 252/256, no slack to hoist
// next-ks B loads; B-stream at 21.5 TB/s < 34.5 L2 ceiling. Fix: two
// sequential c-halves (acc 128->64 AGPR, ~60 slots freed), ks at unroll 2
// (one extra iter's 12 B frags ~ 48 regs fits -> legal 1-deep B prefetch).
// R13 lesson: NO full unroll. Everything else bitwise R12 (absmax 0.01757812).
// packed B: [t:32][ks:16][f:6][512] u16, f = {o0h, o0l, o1h, o2h, o3h, o3l}.

typedef __bf16 bf16_t;
typedef bf16_t bf16x8 __attribute__((ext_vector_type(8)));
typedef float f32x4 __attribute__((ext_vector_type(4)));
typedef _Float16 h2_t __attribute__((ext_vector_type(2)));

#define B_ROWS 32768
#define D_DIM 512
#define N_DEPTH 7
#define BD ((size_t)B_ROWS * D_DIM)

__device__ __forceinline__ unsigned short f2b(float f) {
  bf16_t h = (bf16_t)f;
  return __builtin_bit_cast(unsigned short, h);
}
__device__ __forceinline__ float b2f(unsigned short u) {
  bf16_t h = __builtin_bit_cast(bf16_t, u);
  return (float)h;
}
__device__ __forceinline__ float fast_tanh(float x) {
  float ax = fabsf(x);
  float e = __expf(2.0f * ax);
  float t = 1.0f - 2.0f / (e + 1.0f);
  return copysignf(t, x);
}
// LDS plane: [32 rows][512 bf16], 1KB/row, XOR swizzle on bits 4-6.
__device__ __forceinline__ int lds_addr(int row, int byte_in_row) {
  return row * 1024 + (byte_in_row ^ ((row & 7) << 4));
}

// B-fragment map (mfma_f32_16x16x32_bf16): col = lane&15, k = (lane>>4)*8+i.
__global__ __launch_bounds__(256) void prepack_v2(
    const float* __restrict__ cm, const float* __restrict__ h1,
    const float* __restrict__ h2, const float* __restrict__ h3,
    const float* __restrict__ h5, unsigned short* __restrict__ dst) {
  int gid = blockIdx.x * 256 + threadIdx.x;  // 0..32767
  if (gid >= 32 * 16 * 64) return;
  int l  = gid & 63;
  int ks = (gid >> 6) & 15;
  int t  = gid >> 10;
  int n  = t * 16 + (l & 15);
  int k0 = ks * 32 + (l >> 4) * 8;
  unsigned short* base = dst + ((size_t)(t * 16 + ks) * 6) * 512 + l * 8;
  bf16x8 f0, f1, f2, f3, f4, f5;
#pragma unroll
  for (int i = 0; i < 8; ++i) {
    size_t idx = (size_t)(k0 + i) * D_DIM + n;
    float v0 = cm[idx] + h1[idx];
    unsigned short h0 = f2b(v0);
    f0[i] = __builtin_bit_cast(bf16_t, h0);
    f1[i] = (bf16_t)(v0 - b2f(h0));
    f2[i] = (bf16_t)h2[idx];
    f3[i] = (bf16_t)h3[idx];
    float v5 = h5[idx];
    unsigned short h5v = f2b(v5);
    f4[i] = __builtin_bit_cast(bf16_t, h5v);
    f5[i] = (bf16_t)(v5 - b2f(h5v));
  }
  *(bf16x8*)(base + 0 * 512) = f0;
  *(bf16x8*)(base + 1 * 512) = f1;
  *(bf16x8*)(base + 2 * 512) = f2;
  *(bf16x8*)(base + 3 * 512) = f3;
  *(bf16x8*)(base + 4 * 512) = f4;
  *(bf16x8*)(base + 5 * 512) = f5;
}

__global__ __launch_bounds__(512) void resonance_kernel(
    const float* __restrict__ wr, const float* __restrict__ wi,
    const float* __restrict__ scale, const float* __restrict__ bias,
    const unsigned short* __restrict__ pre, float* __restrict__ out) {
  __shared__ unsigned short lds_hi[2][32 * 512];  // 2 x 32KB
  __shared__ unsigned short lds_lo[2][32 * 512];  // 2 x 32KB

  const int tid  = threadIdx.x;
  const int lane = tid & 63;
  const int wave = tid >> 6;   // 0..7
  const int ln15 = lane & 15;
  const int lg   = lane >> 4;  // 0..3
  const int r0   = blockIdx.x * 16;  // 16 complex rows per block

  // ---- stage initial wave into buffer 0 (GEMM rows: 0-15 re, 16-31 im) ----
#pragma unroll
  for (int it = 0; it < 4; ++it) {
    int idx = it * 512 + tid;  // 0..2047, 8 elems each
    int row = idx >> 6;        // 0..31
    int k0  = (idx & 63) * 8;
    const float* src = (row < 16)
        ? (wr + (size_t)(r0 + row) * D_DIM + k0)
        : (wi + (size_t)(r0 + row - 16) * D_DIM + k0);
    float4 v0 = *(const float4*)(src);
    float4 v1 = *(const float4*)(src + 4);
    float v[8] = {v0.x, v0.y, v0.z, v0.w, v1.x, v1.y, v1.z, v1.w};
    bf16x8 ph, pl;
#pragma unroll
    for (int j = 0; j < 8; ++j) {
      unsigned short h = f2b(v[j]);
      ph[j] = __builtin_bit_cast(bf16_t, h);
      pl[j] = (bf16_t)(v[j] - b2f(h));
    }
    int ad = lds_addr(row, k0 * 2);
    *(bf16x8*)((char*)lds_hi[0] + ad) = ph;
    *(bf16x8*)((char*)lds_lo[0] + ad) = pl;
  }
  __syncthreads();

  float Wsum = 0.0f;
#pragma unroll
  for (int d = 0; d < N_DEPTH; ++d) Wsum += __expf(-(float)d * (1.0f / 3.0f));
  const float invW = 1.0f / Wsum;

  h2_t oacc[4][4];  // [chunk][r] packed fp16 (re, im) output accumulator
#pragma unroll
  for (int c = 0; c < 4; ++c)
#pragma unroll
    for (int r = 0; r < 4; ++r) oacc[c][r] = (h2_t){(_Float16)0.f, (_Float16)0.f};

  int cur = 0;
  for (int depth = 0; depth < N_DEPTH; ++depth) {
    const float wd = __expf(-(float)depth * (1.0f / 3.0f)) * invW;
    const char* Ahi = (const char*)lds_hi[cur];
    const char* Alo = (const char*)lds_lo[cur];
    char* Nhi = (char*)lds_hi[cur ^ 1];
    char* Nlo = (char*)lds_lo[cur ^ 1];

#pragma unroll
    for (int half = 0; half < 2; ++half) {
      f32x4 acc0[2][2], acc1[2][2], acc2[2][2], acc3[2][2];  // [ci][mt] 64 AGPR
#pragma unroll
      for (int ci = 0; ci < 2; ++ci)
#pragma unroll
        for (int mt = 0; mt < 2; ++mt) {
          acc0[ci][mt] = (f32x4){0.f, 0.f, 0.f, 0.f};
          acc1[ci][mt] = (f32x4){0.f, 0.f, 0.f, 0.f};
          acc2[ci][mt] = (f32x4){0.f, 0.f, 0.f, 0.f};
          acc3[ci][mt] = (f32x4){0.f, 0.f, 0.f, 0.f};
        }

      const unsigned short* bp0 = pre +
          ((size_t)(((half * 2 + 0) * 8 + wave) * 16) * 6 + 3) * 512 + lane * 8;
      const unsigned short* bp1 = pre +
          ((size_t)(((half * 2 + 1) * 8 + wave) * 16) * 6 + 3) * 512 + lane * 8;

#pragma unroll 2
      for (int ks = 0; ks < 16; ++ks) {
        bf16x8 ah[2], al[2];  // one A-load pair feeds both chunks
#pragma unroll
        for (int mt = 0; mt < 2; ++mt) {
          int ad = lds_addr(mt * 16 + ln15, ks * 64 + lg * 16);
          ah[mt] = *(const bf16x8*)(Ahi + ad);
          al[mt] = *(const bf16x8*)(Alo + ad);
        }
#pragma unroll
        for (int ci = 0; ci < 2; ++ci) {
          const unsigned short* bb = (ci == 0) ? bp0 : bp1;
          bf16x8 b0h = *(const bf16x8*)(bb - 1536);
          bf16x8 b0l = *(const bf16x8*)(bb - 1024);
          bf16x8 b1h = *(const bf16x8*)(bb - 512);
          bf16x8 b2h = *(const bf16x8*)(bb);
          bf16x8 b3h = *(const bf16x8*)(bb + 512);
          bf16x8 b3l = *(const bf16x8*)(bb + 1024);
#pragma unroll
          for (int mt = 0; mt < 2; ++mt) {
            acc0[ci][mt] = __builtin_amdgcn_mfma_f32_16x16x32_bf16(ah[mt], b0h, acc0[ci][mt], 0, 0, 0);
            acc0[ci][mt] = __builtin_amdgcn_mfma_f32_16x16x32_bf16(al[mt], b0h, acc0[ci][mt], 0, 0, 0);
            acc0[ci][mt] = __builtin_amdgcn_mfma_f32_16x16x32_bf16(ah[mt], b0l, acc0[ci][mt], 0, 0, 0);
            acc1[ci][mt] = __builtin_amdgcn_mfma_f32_16x16x32_bf16(ah[mt], b1h, acc1[ci][mt], 0, 0, 0);
            acc2[ci][mt] = __builtin_amdgcn_mfma_f32_16x16x32_bf16(ah[mt], b2h, acc2[ci][mt], 0, 0, 0);
            acc3[ci][mt] = __builtin_amdgcn_mfma_f32_16x16x32_bf16(ah[mt], b3h, acc3[ci][mt], 0, 0, 0);
            acc3[ci][mt] = __builtin_amdgcn_mfma_f32_16x16x32_bf16(al[mt], b3h, acc3[ci][mt], 0, 0, 0);
            acc3[ci][mt] = __builtin_amdgcn_mfma_f32_16x16x32_bf16(ah[mt], b3l, acc3[ci][mt], 0, 0, 0);
          }
        }
        bp0 += 3072;
        bp1 += 3072;
      }

      // ---- elementwise for this half's 2 chunks ----
#pragma unroll
      for (int ci = 0; ci < 2; ++ci) {
        const int c = half * 2 + ci;
        const int t = c * 8 + wave;
        const int col = t * 16 + ln15;
        const float sclv = scale[col];
        const float biav = bias[col];
        const float damp = 0.1f / (1.0f + __expf(3.0f * (float)col * (1.0f / 511.0f)));
        const float fac  = __expf(-damp * (float)depth);
#pragma unroll
        for (int r = 0; r < 4; ++r) {
          const int brow = lg * 4 + r;  // complex row 0..15
          float lr = acc0[ci][0][r],  li = acc0[ci][1][r];   // coupling + h1
          float re2 = acc1[ci][0][r], im2 = acc1[ci][1][r];
          float ar = 0.25f * (re2 * re2 + im2 * im2);        // h2 real
          float re3 = acc2[ci][0][r], im3 = acc2[ci][1][r];
          float m3 = re3 * re3 + im3 * im3;
          ar += 0.111111111f * m3 * re3;                     // h3
          float ai = 0.111111111f * m3 * im3;
          float re5 = acc3[ci][0][r], im5 = acc3[ci][1][r];
          float m5 = re5 * re5 + im5 * im5;
          {
            // h5 = |hw|^(1/5) exp(i 5 ang) / 25
            float m5c = fmaxf(m5, 1e-36f);
            float inv = rsqrtf(m5c);
            float ur = re5 * inv, ui = im5 * inv;
            float u2r = ur * ur - ui * ui,     u2i = 2.0f * ur * ui;
            float u4r = u2r * u2r - u2i * u2i, u4i = 2.0f * u2r * u2i;
            float u5r = u4r * ur - u4i * ui,   u5i = u4r * ui + u4i * ur;
            float mag = __expf(0.1f * __logf(m5c));
            float msk = (m5 > 1e-36f) ? 0.04f : 0.0f;
            ar += msk * mag * u5r;
            ai += msk * mag * u5i;
          }
          float ir = lr + ar, ii = li + ai;
          const int colb = col * 2;
          const int ar_ = lds_addr(brow, colb);
          const int ai_ = lds_addr(brow + 16, colb);
          if (depth > 0) {  // interference: old chamber = cur buffer (hi+lo)
            ir += b2f(*(const unsigned short*)(Ahi + ar_))
                + b2f(*(const unsigned short*)(Alo + ar_));
            ii += b2f(*(const unsigned short*)(Ahi + ai_))
                + b2f(*(const unsigned short*)(Alo + ai_));
          }
          float cre = fast_tanh(ir * sclv + biav) * fac;
          float cim = fast_tanh(ii * sclv + biav) * fac;
          oacc[c][r] += (h2_t){(_Float16)(wd * cre), (_Float16)(wd * cim)};
          if (depth < N_DEPTH - 1) {  // state into next buffer
            unsigned short hr = f2b(cre);
            unsigned short hi = f2b(cim);
            *(unsigned short*)(Nhi + ar_) = hr;
            *(unsigned short*)(Nlo + ar_) = f2b(cre - b2f(hr));
            *(unsigned short*)(Nhi + ai_) = hi;
            *(unsigned short*)(Nlo + ai_) = f2b(cim - b2f(hi));
          }
        }
      }
    }
    __syncthreads();  // next buffer fully written before next depth reads it
    cur ^= 1;
  }

  // ---- write weighted sum ----
#pragma unroll
  for (int c = 0; c < 4; ++c) {
    const int col = (c * 8 + wave) * 16 + ln15;
#pragma unroll
    for (int r = 0; r < 4; ++r) {
      int brow = lg * 4 + r;
      size_t base = (size_t)(r0 + brow) * D_DIM + col;
      out[base] = (float)oacc[c][r][0];
      out[BD + base] = (float)oacc[c][r][1];
    }
  }
}

extern "C" void kernel_launch(void* const* d_in, const int* in_sizes, int n_in,
                              void* d_out, int out_size, void* d_ws, size_t ws_size,
                              hipStream_t stream) {
  const float* wr = (const float*)d_in[0];
  const float* wi = (const float*)d_in[1];
  const float* cm = (const float*)d_in[2];
  const float* h1 = (const float*)d_in[3];
  const float* h2 = (const float*)d_in[4];
  const float* h3 = (const float*)d_in[5];
  const float* h5 = (const float*)d_in[6];
  const float* sc = (const float*)d_in[7];
  const float* bi = (const float*)d_in[8];
  unsigned short* pre = (unsigned short*)d_ws;  // 3MB packed B
  float* out = (float*)d_out;

  hipLaunchKernelGGL(prepack_v2, dim3(128), dim3(256), 0, stream,
                     cm, h1, h2, h3, h5, pre);
  hipLaunchKernelGGL(resonance_kernel, dim3(B_ROWS / 16), dim3(512), 0, stream,
                     wr, wi, sc, bi, pre, out);
}

// Round 16
// 1945.845 us; speedup vs baseline: 6.0321x; 1.0311x over previous
//
#include <hip/hip_runtime.h>
#include <hip/hip_bf16.h>
#include <cstdint>

// ChromaticResonance R16: 4 waves/SIMD with R12's single-pass economy.
// R12 (252 regs) and R15 (168 regs) both plateau at ~2000us, MfmaUtil 40%,
// no pipe saturated, occ 24% -> wave-level latency tolerance is the wall.
// Fix: 1024-thread blocks (16 waves = 4/SIMD), 16 complex rows/block (B
// traffic unchanged 43GB), TWO sequential c-phases per depth (1 ntile each:
// acc 32 AGPR, live B 24 -> ~112 total/wave <= 128, ~16 slack), 128KB
// double-buffered LDS state, interference read from cur LDS buffer (no news
// regs), one barrier/depth. Math chain order identical to R12/R15 ->
// absmax bitwise 0.01757812.
// packed B: [t:32][ks:16][f:6][512] u16, f = {o0h, o0l, o1h, o2h, o3h, o3l}.

typedef __bf16 bf16_t;
typedef bf16_t bf16x8 __attribute__((ext_vector_type(8)));
typedef float f32x4 __attribute__((ext_vector_type(4)));
typedef _Float16 h2_t __attribute__((ext_vector_type(2)));

#define B_ROWS 32768
#define D_DIM 512
#define N_DEPTH 7
#define BD ((size_t)B_ROWS * D_DIM)

__device__ __forceinline__ unsigned short f2b(float f) {
  bf16_t h = (bf16_t)f;
  return __builtin_bit_cast(unsigned short, h);
}
__device__ __forceinline__ float b2f(unsigned short u) {
  bf16_t h = __builtin_bit_cast(bf16_t, u);
  return (float)h;
}
__device__ __forceinline__ float fast_tanh(float x) {
  float ax = fabsf(x);
  float e = __expf(2.0f * ax);
  float t = 1.0f - 2.0f / (e + 1.0f);
  return copysignf(t, x);
}
// LDS plane: [32 rows][512 bf16], 1KB/row, XOR swizzle on bits 4-6.
__device__ __forceinline__ int lds_addr(int row, int byte_in_row) {
  return row * 1024 + (byte_in_row ^ ((row & 7) << 4));
}

// B-fragment map (mfma_f32_16x16x32_bf16): col = lane&15, k = (lane>>4)*8+i.
__global__ __launch_bounds__(256) void prepack_v2(
    const float* __restrict__ cm, const float* __restrict__ h1,
    const float* __restrict__ h2, const float* __restrict__ h3,
    const float* __restrict__ h5, unsigned short* __restrict__ dst) {
  int gid = blockIdx.x * 256 + threadIdx.x;  // 0..32767
  if (gid >= 32 * 16 * 64) return;
  int l  = gid & 63;
  int ks = (gid >> 6) & 15;
  int t  = gid >> 10;
  int n  = t * 16 + (l & 15);
  int k0 = ks * 32 + (l >> 4) * 8;
  unsigned short* base = dst + ((size_t)(t * 16 + ks) * 6) * 512 + l * 8;
  bf16x8 f0, f1, f2, f3, f4, f5;
#pragma unroll
  for (int i = 0; i < 8; ++i) {
    size_t idx = (size_t)(k0 + i) * D_DIM + n;
    float v0 = cm[idx] + h1[idx];
    unsigned short h0 = f2b(v0);
    f0[i] = __builtin_bit_cast(bf16_t, h0);
    f1[i] = (bf16_t)(v0 - b2f(h0));
    f2[i] = (bf16_t)h2[idx];
    f3[i] = (bf16_t)h3[idx];
    float v5 = h5[idx];
    unsigned short h5v = f2b(v5);
    f4[i] = __builtin_bit_cast(bf16_t, h5v);
    f5[i] = (bf16_t)(v5 - b2f(h5v));
  }
  *(bf16x8*)(base + 0 * 512) = f0;
  *(bf16x8*)(base + 1 * 512) = f1;
  *(bf16x8*)(base + 2 * 512) = f2;
  *(bf16x8*)(base + 3 * 512) = f3;
  *(bf16x8*)(base + 4 * 512) = f4;
  *(bf16x8*)(base + 5 * 512) = f5;
}

__global__ __launch_bounds__(1024) void resonance_kernel(
    const float* __restrict__ wr, const float* __restrict__ wi,
    const float* __restrict__ scale, const float* __restrict__ bias,
    const unsigned short* __restrict__ pre, float* __restrict__ out) {
  __shared__ unsigned short lds_hi[2][32 * 512];  // 2 x 32KB
  __shared__ unsigned short lds_lo[2][32 * 512];  // 2 x 32KB

  const int tid  = threadIdx.x;
  const int lane = tid & 63;
  const int wave = tid >> 6;   // 0..15
  const int ln15 = lane & 15;
  const int lg   = lane >> 4;  // 0..3
  const int r0   = blockIdx.x * 16;  // 16 complex rows per block

  // ---- stage initial wave into buffer 0 (GEMM rows: 0-15 re, 16-31 im) ----
#pragma unroll
  for (int it = 0; it < 2; ++it) {
    int idx = it * 1024 + tid;  // 0..2047, 8 elems each
    int row = idx >> 6;         // 0..31
    int k0  = (idx & 63) * 8;
    const float* src = (row < 16)
        ? (wr + (size_t)(r0 + row) * D_DIM + k0)
        : (wi + (size_t)(r0 + row - 16) * D_DIM + k0);
    float4 v0 = *(const float4*)(src);
    float4 v1 = *(const float4*)(src + 4);
    float v[8] = {v0.x, v0.y, v0.z, v0.w, v1.x, v1.y, v1.z, v1.w};
    bf16x8 ph, pl;
#pragma unroll
    for (int j = 0; j < 8; ++j) {
      unsigned short h = f2b(v[j]);
      ph[j] = __builtin_bit_cast(bf16_t, h);
      pl[j] = (bf16_t)(v[j] - b2f(h));
    }
    int ad = lds_addr(row, k0 * 2);
    *(bf16x8*)((char*)lds_hi[0] + ad) = ph;
    *(bf16x8*)((char*)lds_lo[0] + ad) = pl;
  }
  __syncthreads();

  float Wsum = 0.0f;
#pragma unroll
  for (int d = 0; d < N_DEPTH; ++d) Wsum += __expf(-(float)d * (1.0f / 3.0f));
  const float invW = 1.0f / Wsum;

  h2_t oacc[2][4];  // [chunk][r] packed fp16 (re, im) output accumulator
#pragma unroll
  for (int c = 0; c < 2; ++c)
#pragma unroll
    for (int r = 0; r < 4; ++r) oacc[c][r] = (h2_t){(_Float16)0.f, (_Float16)0.f};

  int cur = 0;
  for (int depth = 0; depth < N_DEPTH; ++depth) {
    const float wd = __expf(-(float)depth * (1.0f / 3.0f)) * invW;
    const char* Ahi = (const char*)lds_hi[cur];
    const char* Alo = (const char*)lds_lo[cur];
    char* Nhi = (char*)lds_hi[cur ^ 1];
    char* Nlo = (char*)lds_lo[cur ^ 1];

#pragma unroll
    for (int c = 0; c < 2; ++c) {
      const int t = c * 16 + wave;  // ntile 0..31
      f32x4 acc0[2], acc1[2], acc2[2], acc3[2];  // [mt] 32 AGPR
#pragma unroll
      for (int mt = 0; mt < 2; ++mt) {
        acc0[mt] = (f32x4){0.f, 0.f, 0.f, 0.f};
        acc1[mt] = (f32x4){0.f, 0.f, 0.f, 0.f};
        acc2[mt] = (f32x4){0.f, 0.f, 0.f, 0.f};
        acc3[mt] = (f32x4){0.f, 0.f, 0.f, 0.f};
      }

      const unsigned short* bb = pre + ((size_t)(t * 16) * 6 + 3) * 512 + lane * 8;
#pragma unroll 2
      for (int ks = 0; ks < 16; ++ks) {
        bf16x8 ah[2], al[2];
#pragma unroll
        for (int mt = 0; mt < 2; ++mt) {
          int ad = lds_addr(mt * 16 + ln15, ks * 64 + lg * 16);
          ah[mt] = *(const bf16x8*)(Ahi + ad);
          al[mt] = *(const bf16x8*)(Alo + ad);
        }
        bf16x8 b0h = *(const bf16x8*)(bb - 1536);
        bf16x8 b0l = *(const bf16x8*)(bb - 1024);
        bf16x8 b1h = *(const bf16x8*)(bb - 512);
        bf16x8 b2h = *(const bf16x8*)(bb);
        bf16x8 b3h = *(const bf16x8*)(bb + 512);
        bf16x8 b3l = *(const bf16x8*)(bb + 1024);
        bb += 3072;
#pragma unroll
        for (int mt = 0; mt < 2; ++mt) {
          acc0[mt] = __builtin_amdgcn_mfma_f32_16x16x32_bf16(ah[mt], b0h, acc0[mt], 0, 0, 0);
          acc0[mt] = __builtin_amdgcn_mfma_f32_16x16x32_bf16(al[mt], b0h, acc0[mt], 0, 0, 0);
          acc0[mt] = __builtin_amdgcn_mfma_f32_16x16x32_bf16(ah[mt], b0l, acc0[mt], 0, 0, 0);
          acc1[mt] = __builtin_amdgcn_mfma_f32_16x16x32_bf16(ah[mt], b1h, acc1[mt], 0, 0, 0);
          acc2[mt] = __builtin_amdgcn_mfma_f32_16x16x32_bf16(ah[mt], b2h, acc2[mt], 0, 0, 0);
          acc3[mt] = __builtin_amdgcn_mfma_f32_16x16x32_bf16(ah[mt], b3h, acc3[mt], 0, 0, 0);
          acc3[mt] = __builtin_amdgcn_mfma_f32_16x16x32_bf16(al[mt], b3h, acc3[mt], 0, 0, 0);
          acc3[mt] = __builtin_amdgcn_mfma_f32_16x16x32_bf16(ah[mt], b3l, acc3[mt], 0, 0, 0);
        }
      }

      // ---- elementwise: complex rows lg*4+r, col t*16+ln15 ----
      const int col = t * 16 + ln15;
      const float sclv = scale[col];
      const float biav = bias[col];
      const float damp = 0.1f / (1.0f + __expf(3.0f * (float)col * (1.0f / 511.0f)));
      const float fac  = __expf(-damp * (float)depth);
#pragma unroll
      for (int r = 0; r < 4; ++r) {
        const int brow = lg * 4 + r;  // complex row 0..15
        float lr = acc0[0][r],  li = acc0[1][r];   // coupling + h1
        float re2 = acc1[0][r], im2 = acc1[1][r];
        float ar = 0.25f * (re2 * re2 + im2 * im2);  // h2 real
        float re3 = acc2[0][r], im3 = acc2[1][r];
        float m3 = re3 * re3 + im3 * im3;
        ar += 0.111111111f * m3 * re3;               // h3
        float ai = 0.111111111f * m3 * im3;
        float re5 = acc3[0][r], im5 = acc3[1][r];
        float m5 = re5 * re5 + im5 * im5;
        {
          // h5 = |hw|^(1/5) exp(i 5 ang) / 25
          float m5c = fmaxf(m5, 1e-36f);
          float inv = rsqrtf(m5c);
          float ur = re5 * inv, ui = im5 * inv;
          float u2r = ur * ur - ui * ui,     u2i = 2.0f * ur * ui;
          float u4r = u2r * u2r - u2i * u2i, u4i = 2.0f * u2r * u2i;
          float u5r = u4r * ur - u4i * ui,   u5i = u4r * ui + u4i * ur;
          float mag = __expf(0.1f * __logf(m5c));
          float msk = (m5 > 1e-36f) ? 0.04f : 0.0f;
          ar += msk * mag * u5r;
          ai += msk * mag * u5i;
        }
        float ir = lr + ar, ii = li + ai;
        const int colb = col * 2;
        const int ar_ = lds_addr(brow, colb);
        const int ai_ = lds_addr(brow + 16, colb);
        if (depth > 0) {  // interference: old chamber = cur buffer (hi+lo)
          ir += b2f(*(const unsigned short*)(Ahi + ar_))
              + b2f(*(const unsigned short*)(Alo + ar_));
          ii += b2f(*(const unsigned short*)(Ahi + ai_))
              + b2f(*(const unsigned short*)(Alo + ai_));
        }
        float cre = fast_tanh(ir * sclv + biav) * fac;
        float cim = fast_tanh(ii * sclv + biav) * fac;
        oacc[c][r] += (h2_t){(_Float16)(wd * cre), (_Float16)(wd * cim)};
        if (depth < N_DEPTH - 1) {  // state into next buffer
          unsigned short hr = f2b(cre);
          unsigned short hi = f2b(cim);
          *(unsigned short*)(Nhi + ar_) = hr;
          *(unsigned short*)(Nlo + ar_) = f2b(cre - b2f(hr));
          *(unsigned short*)(Nhi + ai_) = hi;
          *(unsigned short*)(Nlo + ai_) = f2b(cim - b2f(hi));
        }
      }
    }
    __syncthreads();  // next buffer fully written before next depth reads it
    cur ^= 1;
  }

  // ---- write weighted sum ----
#pragma unroll
  for (int c = 0; c < 2; ++c) {
    const int col = (c * 16 + wave) * 16 + ln15;
#pragma unroll
    for (int r = 0; r < 4; ++r) {
      int brow = lg * 4 + r;
      size_t base = (size_t)(r0 + brow) * D_DIM + col;
      out[base] = (float)oacc[c][r][0];
      out[BD + base] = (float)oacc[c][r][1];
    }
  }
}

extern "C" void kernel_launch(void* const* d_in, const int* in_sizes, int n_in,
                              void* d_out, int out_size, void* d_ws, size_t ws_size,
                              hipStream_t stream) {
  const float* wr = (const float*)d_in[0];
  const float* wi = (const float*)d_in[1];
  const float* cm = (const float*)d_in[2];
  const float* h1 = (const float*)d_in[3];
  const float* h2 = (const float*)d_in[4];
  const float* h3 = (const float*)d_in[5];
  const float* h5 = (const float*)d_in[6];
  const float* sc = (const float*)d_in[7];
  const float* bi = (const float*)d_in[8];
  unsigned short* pre = (unsigned short*)d_ws;  // 3MB packed B
  float* out = (float*)d_out;

  hipLaunchKernelGGL(prepack_v2, dim3(128), dim3(256), 0, stream,
                     cm, h1, h2, h3, h5, pre);
  hipLaunchKernelGGL(resonance_kernel, dim3(B_ROWS / 16), dim3(1024), 0, stream,
                     wr, wi, sc, bi, pre, out);
}